// Round 3
// baseline (186.860 us; speedup 1.0000x reference)
//
#include <hip/hip_runtime.h>
#include <hip/hip_bf16.h>
#include <stdint.h>

#define KDIM 4096
#define BM 128
#define BN 128
#define BK 32
#define KSPLIT 2
#define KHALF (KDIM / KSPLIT)

typedef __attribute__((ext_vector_type(8))) short bf16x8;
typedef __attribute__((ext_vector_type(4))) float f32x4;

__device__ inline unsigned short f2bf_bits(float f) {
  union { __hip_bfloat16 h; unsigned short u; } cv;
  cv.h = __float2bfloat16(f);
  return cv.u;
}

// Fused quant+dequant for both tensors. One 8-lane subgroup = one 32-elem block.
// Palette selection via per-block thresholds (1 mul + 7 cmp/select per element,
// no per-element division). Thresholds are palette midpoints / 6 * block_max;
// ties (a == T) go to the LOWER palette value, matching argmin-first semantics.
__global__ void nvfp4_quant_dq2(const float* __restrict__ x, unsigned short* __restrict__ xq,
                                int nsub_x,
                                const float* __restrict__ w, unsigned short* __restrict__ wq,
                                int nsub_total) {
  int gid = blockIdx.x * blockDim.x + threadIdx.x;
  int sub = gid >> 3;
  if (sub >= nsub_total) return;
  const float* in;
  unsigned short* out;
  if (sub < nsub_x) { in = x; out = xq; }
  else { in = w; out = wq; sub -= nsub_x; }
  long base = (long)sub * 32 + (long)(gid & 7) * 4;
  const float4 v = *(const float4*)(in + base);
  float amax = fmaxf(fmaxf(fabsf(v.x), fabsf(v.y)), fmaxf(fabsf(v.z), fabsf(v.w)));
  amax = fmaxf(amax, __shfl_xor(amax, 1));
  amax = fmaxf(amax, __shfl_xor(amax, 2));
  amax = fmaxf(amax, __shfl_xor(amax, 4));
  const float bm = fmaxf(amax, 1e-12f);   // jnp.clip(max, 1e-12)
  const float scale = bm / 6.0f;          // matches reference's block_max / 6

  const float T0 = bm * (0.25f / 6.0f);
  const float T1 = bm * (0.75f / 6.0f);
  const float T2 = bm * (1.25f / 6.0f);
  const float T3 = bm * (1.75f / 6.0f);
  const float T4 = bm * (2.5f  / 6.0f);
  const float T5 = bm * (3.5f  / 6.0f);
  const float T6 = bm * (5.0f  / 6.0f);

  float e[4] = {v.x, v.y, v.z, v.w};
  ushort4 o;
  unsigned short* op = (unsigned short*)&o;
#pragma unroll
  for (int i = 0; i < 4; i++) {
    float t = e[i];
    float a = fabsf(t);
    float p = 0.0f;
    p = (a > T0) ? 0.5f : p;
    p = (a > T1) ? 1.0f : p;
    p = (a > T2) ? 1.5f : p;
    p = (a > T3) ? 2.0f : p;
    p = (a > T4) ? 3.0f : p;
    p = (a > T5) ? 4.0f : p;
    p = (a > T6) ? 6.0f : p;
    op[i] = f2bf_bits(copysignf(p, t) * scale);
  }
  *(ushort4*)(out + base) = o;
}

// C[M,N] += A[M,K](bf16) * B[N,K]^T(bf16) over K-half blockIdx.z.
// 128x128 tile, BK=32, 4 waves (2x2), each wave 64x64 via 4x4 grid of
// 16x16x32 MFMA. Grid (N/128, M/128, 2) = 512 blocks -> 2 blocks/CU.
// Epilogue: fp32 atomicAdd (exactly 2 partials + zero init -> deterministic).
__global__ __launch_bounds__(256, 2) void gemm_bf16_bt_sk(
    const unsigned short* __restrict__ A,  // [M, K]
    const unsigned short* __restrict__ B,  // [N, K]
    float* __restrict__ C, int M, int N) {
  __shared__ unsigned short As[BM * BK];   // 8 KB
  __shared__ unsigned short Bs[BN * BK];   // 8 KB

  const int tid = threadIdx.x;
  const int wave = tid >> 6;
  const int lane = tid & 63;
  const int wm = wave >> 1;       // 0..1
  const int wn = wave & 1;        // 0..1
  const int quad = lane >> 4;     // 0..3
  const int r16 = lane & 15;      // 0..15

  const int bm0 = blockIdx.y * BM;
  const int bn0 = blockIdx.x * BN;
  const int kb = blockIdx.z * KHALF;

  // Staging: chunk cc (0..7) = 1 KB = 16 rows x 32 k. Each wave: 2 chunks of A,
  // 2 of B (4 x 16B global_load_lds per K-step). LDS dest = uniform base + lane*16B.
  const int cc = wave * 2;
  const int rstg = lane >> 2;          // 0..15
  const int kstg = (lane & 3) * 8;     // 0,8,16,24

  const unsigned short* aptr0 = A + (long)(bm0 + cc * 16 + rstg) * KDIM + kb + kstg;
  const unsigned short* aptr1 = aptr0 + 16 * KDIM;
  const unsigned short* bptr0 = B + (long)(bn0 + cc * 16 + rstg) * KDIM + kb + kstg;
  const unsigned short* bptr1 = bptr0 + 16 * KDIM;

  unsigned short* lA0 = As + cc * 512 + lane * 8;
  unsigned short* lA1 = As + (cc + 1) * 512 + lane * 8;
  unsigned short* lB0 = Bs + cc * 512 + lane * 8;
  unsigned short* lB1 = Bs + (cc + 1) * 512 + lane * 8;

  f32x4 acc[4][4] = {};

  for (int k0 = 0; k0 < KHALF; k0 += BK) {
    __builtin_amdgcn_global_load_lds(
        (const __attribute__((address_space(1))) void*)aptr0,
        (__attribute__((address_space(3))) void*)lA0, 16, 0, 0);
    __builtin_amdgcn_global_load_lds(
        (const __attribute__((address_space(1))) void*)aptr1,
        (__attribute__((address_space(3))) void*)lA1, 16, 0, 0);
    __builtin_amdgcn_global_load_lds(
        (const __attribute__((address_space(1))) void*)bptr0,
        (__attribute__((address_space(3))) void*)lB0, 16, 0, 0);
    __builtin_amdgcn_global_load_lds(
        (const __attribute__((address_space(1))) void*)bptr1,
        (__attribute__((address_space(3))) void*)lB1, 16, 0, 0);
    aptr0 += BK; aptr1 += BK; bptr0 += BK; bptr1 += BK;

    __syncthreads();

    bf16x8 af[4], bf[4];
#pragma unroll
    for (int i = 0; i < 4; i++) {
      const int arow = wm * 64 + i * 16 + r16;
      af[i] = *(const bf16x8*)(As + arow * BK + quad * 8);
      const int brow = wn * 64 + i * 16 + r16;
      bf[i] = *(const bf16x8*)(Bs + brow * BK + quad * 8);
    }

#pragma unroll
    for (int i = 0; i < 4; i++)
#pragma unroll
      for (int j = 0; j < 4; j++)
        acc[i][j] = __builtin_amdgcn_mfma_f32_16x16x32_bf16(af[i], bf[j], acc[i][j], 0, 0, 0);

    __syncthreads();
  }

  // Epilogue: C/D layout col = lane&15, row = quad*4 + reg
#pragma unroll
  for (int i = 0; i < 4; i++) {
#pragma unroll
    for (int j = 0; j < 4; j++) {
      const int row = bm0 + wm * 64 + i * 16 + quad * 4;
      const int col = bn0 + wn * 64 + j * 16 + r16;
#pragma unroll
      for (int r = 0; r < 4; r++)
        atomicAdd(&C[(long)(row + r) * N + col], acc[i][j][r]);
    }
  }
}

extern "C" void kernel_launch(void* const* d_in, const int* in_sizes, int n_in,
                              void* d_out, int out_size, void* d_ws, size_t ws_size,
                              hipStream_t stream) {
  const float* x = (const float*)d_in[0];   // [M, K] fp32
  const float* w = (const float*)d_in[1];   // [N, K] fp32
  float* out = (float*)d_out;               // [M, N] fp32

  const int MK = in_sizes[0];
  const int NK = in_sizes[1];
  const int M = MK / KDIM;
  const int N = NK / KDIM;

  unsigned short* xq = (unsigned short*)d_ws;        // [M, K] bf16
  unsigned short* wq = xq + (size_t)MK;              // [N, K] bf16

  // Zero the output for the atomic split-K epilogue (graph-capturable).
  hipMemsetAsync(out, 0, (size_t)out_size * sizeof(float), stream);

  const int nsub_x = MK / 32;
  const int nsub_total = nsub_x + NK / 32;
  nvfp4_quant_dq2<<<dim3((nsub_total * 8 + 255) / 256), dim3(256), 0, stream>>>(
      x, xq, nsub_x, w, wq, nsub_total);

  dim3 grid(N / BN, M / BM, KSPLIT);
  gemm_bf16_bt_sk<<<grid, dim3(256), 0, stream>>>(xq, wq, out, M, N);
}